// Round 9
// baseline (1001.923 us; speedup 1.0000x reference)
//
#include <hip/hip_runtime.h>

#define CAP 64
#define BN_EPS 1e-5f

typedef _Float16 f16;
typedef _Float16 half8 __attribute__((ext_vector_type(8)));
typedef float f32x4 __attribute__((ext_vector_type(4)));

// ---------------- bucket build: CSR-lite with fixed capacity ----------------
__global__ __launch_bounds__(256) void build_buckets(
    const int* __restrict__ ei, int E,
    int* __restrict__ deg, int* __restrict__ bucket)
{
    int e = blockIdx.x * blockDim.x + threadIdx.x;
    if (e >= E) return;
    int src = ei[e];
    int dst = ei[E + e];
    int slot = atomicAdd(&deg[dst], 1);
    if (slot < CAP) bucket[dst * CAP + slot] = src;
}

// ---------------- per-node u/v precompute: u = f@(A-B)+ba, v = f@B ----------
__global__ __launch_bounds__(256) void uv_kernel(
    const float* __restrict__ feat, int ldf, int K, int N,
    const float* __restrict__ wa, const float* __restrict__ ba,
    f16* __restrict__ U, f16* __restrict__ V)
{
    __shared__ float Wlds[2][64][64];
    __shared__ float blds[64];
    int tid = threadIdx.x;
    for (int idx = tid; idx < 2 * K * 64; idx += blockDim.x) {
        int half = idx / (K * 64);
        int rem = idx - half * (K * 64);
        int k = rem >> 6, o = rem & 63;
        float wB = wa[(K + k) * 64 + o];
        Wlds[half][k][o] = (half == 0) ? (wa[k * 64 + o] - wB) : wB;
    }
    if (tid < 64) blds[tid] = ba[tid];
    __syncthreads();

    int t = blockIdx.x * blockDim.x + tid;
    if (t >= 2 * N) return;
    int node = t >> 1, half = t & 1;

    float acc[64];
    #pragma unroll
    for (int o = 0; o < 64; ++o) acc[o] = (half == 0) ? blds[o] : 0.f;

    const float* f = feat + (long)node * ldf;
    for (int k = 0; k < K; ++k) {
        float c = f[k];
        #pragma unroll
        for (int o = 0; o < 64; ++o) acc[o] = fmaf(c, Wlds[half][k][o], acc[o]);
    }
    f16* dstp = (half == 0 ? U : V) + (long)node * 64;
    #pragma unroll
    for (int o = 0; o < 64; o += 8) {
        half8 h;
        #pragma unroll
        for (int j = 0; j < 8; ++j) h[j] = (f16)acc[o + j];
        *(half8*)(dstp + o) = h;
    }
}

// ---------------- node kernel: wave per node, MFMA, depth-3 V pipeline ------
// A frag: lane holds A[row=lane&15][k=32*s+8*(lane>>4)+j]
// B frag: lane holds B[k=32*s+8*(lane>>4)+j][col=16*ct+(lane&15)]  (in LDS)
// D frag: lane holds D[row=4*(lane>>4)+r][col=16*ct+(lane&15)]
__global__ __launch_bounds__(256, 8) void node_kernel(
    const f16* __restrict__ U, const f16* __restrict__ V,
    const int* __restrict__ deg, const int* __restrict__ bucket,
    const float* __restrict__ wb, const float* __restrict__ bb,
    const float* __restrict__ bng, const float* __restrict__ bnb,
    const float* __restrict__ bnm, const float* __restrict__ bnv,
    int N, float* __restrict__ Fout)
{
    const int lane = threadIdx.x & 63;
    const int r16 = lane >> 4, c16 = lane & 15;
    const int wid = (blockIdx.x * blockDim.x + threadIdx.x) >> 6;
    const int nwaves = (gridDim.x * blockDim.x) >> 6;

    // Wb fragments in LDS: WB[f=ct*2+s][lane] = half8 (8 KB). Frees 32 VGPR.
    __shared__ half8 WB[8][64];
    for (int idx = threadIdx.x; idx < 8 * 64; idx += blockDim.x) {
        int f = idx >> 6, l = idx & 63;
        int lr = l >> 4, lc = l & 15;
        int s = f & 1, ct = f >> 1;
        half8 h;
        #pragma unroll
        for (int j = 0; j < 8; ++j) {
            int k = 32 * s + 8 * lr + j;
            h[j] = (f16)wb[k * 64 + 16 * ct + lc];
        }
        WB[f][l] = h;
    }
    __syncthreads();

    const float bbv = bb[lane];
    const float g = bng[lane], be = bnb[lane];
    const float rs = rsqrtf(bnv[lane] + BN_EPS), mm = bnm[lane];

    int chunk = (N + nwaves - 1) / nwaves;
    int n0 = wid * chunk;
    int n1 = n0 + chunk; if (n1 > N) n1 = N;
    if (n0 >= n1) return;

    // block-load this chunk's degrees (chunk <= 64), access via shfl
    int dval = 0;
    if (lane < n1 - n0) dval = deg[n0 + lane];
    dval = dval > CAP ? CAP : dval;

    auto nclamp = [&](int n) { return n < n1 ? n : n1 - 1; };

    // prologue: bucket rows for n0..n0+2; V gathers for n0, n0+1; U for n0
    int bkt0 = bucket[(long)n0 * CAP + c16];
    int bkt1 = bucket[(long)nclamp(n0 + 1) * CAP + c16];
    int bkt2 = bucket[(long)nclamp(n0 + 2) * CAP + c16];

    unsigned s0 = (unsigned)bkt0 < (unsigned)N ? (unsigned)bkt0 : 0u;
    unsigned s1 = (unsigned)bkt1 < (unsigned)N ? (unsigned)bkt1 : 0u;
    const half8* vp0 = (const half8*)(V + (long)s0 * 64);
    const half8* vp1 = (const half8*)(V + (long)s1 * 64);
    half8 v0A = vp0[r16], v0B = vp0[4 + r16];
    half8 v1A = vp1[r16], v1B = vp1[4 + r16];
    const half8* up0 = (const half8*)(U + (long)n0 * 64);
    half8 u0A = up0[r16], u0B = up0[4 + r16];

    for (int node = n0; node < n1; ++node) {
        // issue: V gather for node+2 (bkt2 loaded 2 iters ago)
        unsigned s2 = (unsigned)bkt2 < (unsigned)N ? (unsigned)bkt2 : 0u;
        const half8* vp2 = (const half8*)(V + (long)s2 * 64);
        half8 v2A = vp2[r16], v2B = vp2[4 + r16];
        // issue: bucket row for node+3
        int bkt3 = bucket[(long)nclamp(node + 3) * CAP + c16];
        // issue: U row for node+1
        const half8* up1 = (const half8*)(U + (long)nclamp(node + 1) * 64);
        half8 u1A = up1[r16], u1B = up1[4 + r16];

        int d = __shfl(dval, node - n0);

        float m0 = -INFINITY, m1 = -INFINITY, m2 = -INFINITY, m3 = -INFINITY;
        int ntile = (d + 15) >> 4;

        if (ntile > 0) {
            // tile 0: data already gathered (v0A/v0B)
            half8 a0 = v0A + u0A;
            half8 a1 = v0B + u0B;
            #pragma unroll
            for (int j = 0; j < 8; ++j) {
                a0[j] = a0[j] > (f16)0 ? a0[j] : (f16)0;
                a1[j] = a1[j] > (f16)0 ? a1[j] : (f16)0;
            }
            const f32x4 z = {0.f, 0.f, 0.f, 0.f};
            #pragma unroll
            for (int ct = 0; ct < 4; ++ct) {
                f32x4 acc = __builtin_amdgcn_mfma_f32_16x16x32_f16(a0, WB[ct * 2 + 0][lane], z, 0, 0, 0);
                acc = __builtin_amdgcn_mfma_f32_16x16x32_f16(a1, WB[ct * 2 + 1][lane], acc, 0, 0, 0);
                float mx = -INFINITY;
                #pragma unroll
                for (int r = 0; r < 4; ++r) {
                    int row = r16 * 4 + r;
                    float val = (row < d) ? acc[r] : -INFINITY;
                    mx = fmaxf(mx, val);
                }
                mx = fmaxf(mx, __shfl_xor(mx, 16));
                mx = fmaxf(mx, __shfl_xor(mx, 32));
                if (ct == 0) m0 = fmaxf(m0, mx);
                else if (ct == 1) m1 = fmaxf(m1, mx);
                else if (ct == 2) m2 = fmaxf(m2, mx);
                else m3 = fmaxf(m3, mx);
            }
        }
        // rare tiles (d > 16): serial path
        for (int t = 1; t < ntile; ++t) {
            int bkt = bucket[(long)node * CAP + t * 16 + c16];
            unsigned su = (unsigned)bkt < (unsigned)N ? (unsigned)bkt : 0u;
            const half8* vrt = (const half8*)(V + (long)su * 64);
            half8 a0 = vrt[r16] + u0A;
            half8 a1 = vrt[4 + r16] + u0B;
            #pragma unroll
            for (int j = 0; j < 8; ++j) {
                a0[j] = a0[j] > (f16)0 ? a0[j] : (f16)0;
                a1[j] = a1[j] > (f16)0 ? a1[j] : (f16)0;
            }
            const f32x4 z = {0.f, 0.f, 0.f, 0.f};
            #pragma unroll
            for (int ct = 0; ct < 4; ++ct) {
                f32x4 acc = __builtin_amdgcn_mfma_f32_16x16x32_f16(a0, WB[ct * 2 + 0][lane], z, 0, 0, 0);
                acc = __builtin_amdgcn_mfma_f32_16x16x32_f16(a1, WB[ct * 2 + 1][lane], acc, 0, 0, 0);
                float mx = -INFINITY;
                #pragma unroll
                for (int r = 0; r < 4; ++r) {
                    int row = t * 16 + r16 * 4 + r;
                    float val = (row < d) ? acc[r] : -INFINITY;
                    mx = fmaxf(mx, val);
                }
                mx = fmaxf(mx, __shfl_xor(mx, 16));
                mx = fmaxf(mx, __shfl_xor(mx, 32));
                if (ct == 0) m0 = fmaxf(m0, mx);
                else if (ct == 1) m1 = fmaxf(m1, mx);
                else if (ct == 2) m2 = fmaxf(m2, mx);
                else m3 = fmaxf(m3, mx);
            }
        }

        float sel = (r16 == 0) ? m0 : (r16 == 1) ? m1 : (r16 == 2) ? m2 : m3;
        float aggv = (d > 0) ? sel + bbv : 0.f;
        float bn = (aggv - mm) * rs * g + be;
        Fout[(long)node * 64 + lane] = fmaxf(bn, 0.f);

        // rotate pipeline registers
        v0A = v1A; v0B = v1B; v1A = v2A; v1B = v2B;
        u0A = u1A; u0B = u1B;
        bkt2 = bkt3;
    }
}

// ---------------- dense head: thread per node -------------------------------
__global__ __launch_bounds__(256) void head_kernel(
    const float* __restrict__ F,
    const float* __restrict__ lw1, const float* __restrict__ lb1,
    const float* __restrict__ lw2, const float* __restrict__ lb2,
    const float* __restrict__ lw3, const float* __restrict__ lb3,
    const float* __restrict__ lw4, const float* __restrict__ lb4,
    int N, float* __restrict__ out)
{
    __shared__ float W1[64][64];
    __shared__ float W2[64][32];
    __shared__ float W3[32][16];
    __shared__ float W4[16][3];
    __shared__ float B1[64], B2[32], B3[16], B4[3];
    int tid = threadIdx.x;
    for (int i = tid; i < 64 * 64; i += blockDim.x) W1[i >> 6][i & 63] = lw1[i];
    for (int i = tid; i < 64 * 32; i += blockDim.x) W2[i >> 5][i & 31] = lw2[i];
    for (int i = tid; i < 32 * 16; i += blockDim.x) W3[i >> 4][i & 15] = lw3[i];
    for (int i = tid; i < 16 * 3;  i += blockDim.x) W4[i / 3][i % 3]  = lw4[i];
    if (tid < 64) B1[tid] = lb1[tid];
    if (tid < 32) B2[tid] = lb2[tid];
    if (tid < 16) B3[tid] = lb3[tid];
    if (tid < 3)  B4[tid] = lb4[tid];
    __syncthreads();

    int n = blockIdx.x * blockDim.x + tid;
    if (n >= N) return;
    const float* f = F + (long)n * 64;

    float h1[64];
    #pragma unroll
    for (int o = 0; o < 64; ++o) h1[o] = B1[o];
    for (int k = 0; k < 64; ++k) {
        float c = f[k];
        #pragma unroll
        for (int o = 0; o < 64; ++o) h1[o] = fmaf(c, W1[k][o], h1[o]);
    }
    float h2[32];
    #pragma unroll
    for (int o = 0; o < 32; ++o) h2[o] = B2[o];
    #pragma unroll
    for (int k = 0; k < 64; ++k) {
        float c = fmaxf(h1[k], 0.f);
        #pragma unroll
        for (int o = 0; o < 32; ++o) h2[o] = fmaf(c, W2[k][o], h2[o]);
    }
    float h3[16];
    #pragma unroll
    for (int o = 0; o < 16; ++o) h3[o] = B3[o];
    #pragma unroll
    for (int k = 0; k < 32; ++k) {
        float c = fmaxf(h2[k], 0.f);
        #pragma unroll
        for (int o = 0; o < 16; ++o) h3[o] = fmaf(c, W3[k][o], h3[o]);
    }
    float o0 = B4[0], o1 = B4[1], o2 = B4[2];
    #pragma unroll
    for (int k = 0; k < 16; ++k) {
        float c = fmaxf(h3[k], 0.f);
        o0 = fmaf(c, W4[k][0], o0);
        o1 = fmaf(c, W4[k][1], o1);
        o2 = fmaf(c, W4[k][2], o2);
    }
    out[(long)n * 3 + 0] = o0;
    out[(long)n * 3 + 1] = o1;
    out[(long)n * 3 + 2] = o2;
}

// ---------------------------------------------------------------------------
extern "C" void kernel_launch(void* const* d_in, const int* in_sizes, int n_in,
                              void* d_out, int out_size, void* d_ws, size_t ws_size,
                              hipStream_t stream)
{
    const float* x   = (const float*)d_in[0];
    const int*   ei  = (const int*)d_in[1];
    int N = in_sizes[0] / 3;
    int E = in_sizes[1] / 2;

    const float* w1a = (const float*)d_in[2];  const float* b1a = (const float*)d_in[3];
    const float* w1b = (const float*)d_in[4];  const float* b1b = (const float*)d_in[5];
    const float* w2a = (const float*)d_in[6];  const float* b2a = (const float*)d_in[7];
    const float* w2b = (const float*)d_in[8];  const float* b2b = (const float*)d_in[9];
    const float* w3a = (const float*)d_in[10]; const float* b3a = (const float*)d_in[11];
    const float* w3b = (const float*)d_in[12]; const float* b3b = (const float*)d_in[13];
    const float* bn1g = (const float*)d_in[14]; const float* bn1b = (const float*)d_in[15];
    const float* bn1m = (const float*)d_in[16]; const float* bn1v = (const float*)d_in[17];
    const float* bn2g = (const float*)d_in[18]; const float* bn2b = (const float*)d_in[19];
    const float* bn2m = (const float*)d_in[20]; const float* bn2v = (const float*)d_in[21];
    const float* bn3g = (const float*)d_in[22]; const float* bn3b = (const float*)d_in[23];
    const float* bn3m = (const float*)d_in[24]; const float* bn3v = (const float*)d_in[25];
    const float* lw1 = (const float*)d_in[26]; const float* lb1 = (const float*)d_in[27];
    const float* lw2 = (const float*)d_in[28]; const float* lb2 = (const float*)d_in[29];
    const float* lw3 = (const float*)d_in[30]; const float* lb3 = (const float*)d_in[31];
    const float* lw4 = (const float*)d_in[32]; const float* lb4 = (const float*)d_in[33];
    float* out = (float*)d_out;

    // workspace layout (256B aligned slices)
    char* ws = (char*)d_ws;
    size_t off = 0;
    auto alloc = [&](size_t bytes) { void* p = ws + off; off += (bytes + 255) & ~(size_t)255; return p; };
    int*   deg    = (int*)  alloc((size_t)N * sizeof(int));
    int*   bucket = (int*)  alloc((size_t)N * CAP * sizeof(int));
    f16*   U      = (f16*)  alloc((size_t)N * 64 * sizeof(f16));
    f16*   V      = (f16*)  alloc((size_t)N * 64 * sizeof(f16));
    float* F      = (float*)alloc((size_t)N * 64 * sizeof(float));
    (void)ws_size; (void)n_in; (void)out_size;

    hipMemsetAsync(deg, 0, (size_t)N * sizeof(int), stream);
    build_buckets<<<(E + 255) / 256, 256, 0, stream>>>(ei, E, deg, bucket);

    int uv_grid   = (2 * N + 255) / 256;
    int node_blocks = 2048;            // 8192 waves, ~13-node chunks
    int nd_grid   = (N + 255) / 256;

    // layer 1
    uv_kernel<<<uv_grid, 256, 0, stream>>>(x, 3, 3, N, w1a, b1a, U, V);
    node_kernel<<<node_blocks, 256, 0, stream>>>(U, V, deg, bucket, w1b, b1b,
                                                 bn1g, bn1b, bn1m, bn1v, N, F);
    // layer 2
    uv_kernel<<<uv_grid, 256, 0, stream>>>(F, 64, 64, N, w2a, b2a, U, V);
    node_kernel<<<node_blocks, 256, 0, stream>>>(U, V, deg, bucket, w2b, b2b,
                                                 bn2g, bn2b, bn2m, bn2v, N, F);
    // layer 3
    uv_kernel<<<uv_grid, 256, 0, stream>>>(F, 64, 64, N, w3a, b3a, U, V);
    node_kernel<<<node_blocks, 256, 0, stream>>>(U, V, deg, bucket, w3b, b3b,
                                                 bn3g, bn3b, bn3m, bn3v, N, F);
    // head
    head_kernel<<<nd_grid, 256, 0, stream>>>(F, lw1, lb1, lw2, lb2, lw3, lb3,
                                             lw4, lb4, N, out);
}

// Round 10
// 558.195 us; speedup vs baseline: 1.7949x; 1.7949x over previous
//
#include <hip/hip_runtime.h>

#define CAP 64
#define BN_EPS 1e-5f

typedef _Float16 f16;
typedef _Float16 half8 __attribute__((ext_vector_type(8)));
typedef float f32x4 __attribute__((ext_vector_type(4)));

// ---------------- bucket build: CSR-lite with fixed capacity ----------------
__global__ __launch_bounds__(256) void build_buckets(
    const int* __restrict__ ei, int E,
    int* __restrict__ deg, int* __restrict__ bucket)
{
    int e = blockIdx.x * blockDim.x + threadIdx.x;
    if (e >= E) return;
    int src = ei[e];
    int dst = ei[E + e];
    int slot = atomicAdd(&deg[dst], 1);
    if (slot < CAP) bucket[dst * CAP + slot] = src;
}

// ---------------- per-node u/v precompute: u = f@(A-B)+ba, v = f@B ----------
__global__ __launch_bounds__(256) void uv_kernel(
    const float* __restrict__ feat, int ldf, int K, int N,
    const float* __restrict__ wa, const float* __restrict__ ba,
    f16* __restrict__ U, f16* __restrict__ V)
{
    __shared__ float Wlds[2][64][64];
    __shared__ float blds[64];
    int tid = threadIdx.x;
    for (int idx = tid; idx < 2 * K * 64; idx += blockDim.x) {
        int half = idx / (K * 64);
        int rem = idx - half * (K * 64);
        int k = rem >> 6, o = rem & 63;
        float wB = wa[(K + k) * 64 + o];
        Wlds[half][k][o] = (half == 0) ? (wa[k * 64 + o] - wB) : wB;
    }
    if (tid < 64) blds[tid] = ba[tid];
    __syncthreads();

    int t = blockIdx.x * blockDim.x + tid;
    if (t >= 2 * N) return;
    int node = t >> 1, half = t & 1;

    float acc[64];
    #pragma unroll
    for (int o = 0; o < 64; ++o) acc[o] = (half == 0) ? blds[o] : 0.f;

    const float* f = feat + (long)node * ldf;
    for (int k = 0; k < K; ++k) {
        float c = f[k];
        #pragma unroll
        for (int o = 0; o < 64; ++o) acc[o] = fmaf(c, Wlds[half][k][o], acc[o]);
    }
    f16* dstp = (half == 0 ? U : V) + (long)node * 64;
    #pragma unroll
    for (int o = 0; o < 64; o += 8) {
        half8 h;
        #pragma unroll
        for (int j = 0; j < 8; ++j) h[j] = (f16)acc[o + j];
        *(half8*)(dstp + o) = h;
    }
}

// ---------------- node kernel: wave per node, MFMA, depth-3 V pipeline ------
// A frag: lane holds A[row=lane&15][k=32*s+8*(lane>>4)+j]
// B frag: lane holds B[k=32*s+8*(lane>>4)+j][col=16*ct+(lane&15)]  (in LDS)
// D frag: lane holds D[row=4*(lane>>4)+r][col=16*ct+(lane&15)]
// launch_bounds(256,4): VGPR cap 128 — room for the pipeline regs (round-9's
// (256,8) capped at 64 VGPR and spilled: WRITE_SIZE 25->524 MB regression).
__global__ __launch_bounds__(256, 4) void node_kernel(
    const f16* __restrict__ U, const f16* __restrict__ V,
    const int* __restrict__ deg, const int* __restrict__ bucket,
    const float* __restrict__ wb, const float* __restrict__ bb,
    const float* __restrict__ bng, const float* __restrict__ bnb,
    const float* __restrict__ bnm, const float* __restrict__ bnv,
    int N, float* __restrict__ Fout)
{
    const int lane = threadIdx.x & 63;
    const int r16 = lane >> 4, c16 = lane & 15;
    const int wid = (blockIdx.x * blockDim.x + threadIdx.x) >> 6;
    const int nwaves = (gridDim.x * blockDim.x) >> 6;

    // Wb fragments in LDS: WB[f=ct*2+s][lane] = half8 (8 KB).
    __shared__ half8 WB[8][64];
    for (int idx = threadIdx.x; idx < 8 * 64; idx += blockDim.x) {
        int f = idx >> 6, l = idx & 63;
        int lr = l >> 4, lc = l & 15;
        int s = f & 1, ct = f >> 1;
        half8 h;
        #pragma unroll
        for (int j = 0; j < 8; ++j) {
            int k = 32 * s + 8 * lr + j;
            h[j] = (f16)wb[k * 64 + 16 * ct + lc];
        }
        WB[f][l] = h;
    }
    __syncthreads();

    const float bbv = bb[lane];
    const float g = bng[lane], be = bnb[lane];
    const float rs = rsqrtf(bnv[lane] + BN_EPS), mm = bnm[lane];

    int chunk = (N + nwaves - 1) / nwaves;
    int n0 = wid * chunk;
    int n1 = n0 + chunk; if (n1 > N) n1 = N;
    if (n0 >= n1) return;

    // block-load this chunk's degrees (chunk <= 64), access via shfl
    int dval = 0;
    if (lane < n1 - n0) dval = deg[n0 + lane];
    dval = dval > CAP ? CAP : dval;

    auto nclamp = [&](int n) { return n < n1 ? n : n1 - 1; };

    // prologue: bucket rows for n0..n0+2; V gathers for n0, n0+1; U for n0
    int bkt0 = bucket[(long)n0 * CAP + c16];
    int bkt1 = bucket[(long)nclamp(n0 + 1) * CAP + c16];
    int bkt2 = bucket[(long)nclamp(n0 + 2) * CAP + c16];

    unsigned s0 = (unsigned)bkt0 < (unsigned)N ? (unsigned)bkt0 : 0u;
    unsigned s1 = (unsigned)bkt1 < (unsigned)N ? (unsigned)bkt1 : 0u;
    const half8* vp0 = (const half8*)(V + (long)s0 * 64);
    const half8* vp1 = (const half8*)(V + (long)s1 * 64);
    half8 v0A = vp0[r16], v0B = vp0[4 + r16];
    half8 v1A = vp1[r16], v1B = vp1[4 + r16];
    const half8* up0 = (const half8*)(U + (long)n0 * 64);
    half8 u0A = up0[r16], u0B = up0[4 + r16];

    for (int node = n0; node < n1; ++node) {
        // issue: V gather for node+2 (bkt2 loaded 2 iters ago)
        unsigned s2 = (unsigned)bkt2 < (unsigned)N ? (unsigned)bkt2 : 0u;
        const half8* vp2 = (const half8*)(V + (long)s2 * 64);
        half8 v2A = vp2[r16], v2B = vp2[4 + r16];
        // issue: bucket row for node+3
        int bkt3 = bucket[(long)nclamp(node + 3) * CAP + c16];
        // issue: U row for node+1
        const half8* up1 = (const half8*)(U + (long)nclamp(node + 1) * 64);
        half8 u1A = up1[r16], u1B = up1[4 + r16];

        int d = __shfl(dval, node - n0);

        float m0 = -INFINITY, m1 = -INFINITY, m2 = -INFINITY, m3 = -INFINITY;
        int ntile = (d + 15) >> 4;

        if (ntile > 0) {
            // tile 0: data already gathered (v0A/v0B)
            half8 a0 = v0A + u0A;
            half8 a1 = v0B + u0B;
            #pragma unroll
            for (int j = 0; j < 8; ++j) {
                a0[j] = a0[j] > (f16)0 ? a0[j] : (f16)0;
                a1[j] = a1[j] > (f16)0 ? a1[j] : (f16)0;
            }
            const f32x4 z = {0.f, 0.f, 0.f, 0.f};
            #pragma unroll
            for (int ct = 0; ct < 4; ++ct) {
                f32x4 acc = __builtin_amdgcn_mfma_f32_16x16x32_f16(a0, WB[ct * 2 + 0][lane], z, 0, 0, 0);
                acc = __builtin_amdgcn_mfma_f32_16x16x32_f16(a1, WB[ct * 2 + 1][lane], acc, 0, 0, 0);
                float mx = -INFINITY;
                #pragma unroll
                for (int r = 0; r < 4; ++r) {
                    int row = r16 * 4 + r;
                    float val = (row < d) ? acc[r] : -INFINITY;
                    mx = fmaxf(mx, val);
                }
                mx = fmaxf(mx, __shfl_xor(mx, 16));
                mx = fmaxf(mx, __shfl_xor(mx, 32));
                if (ct == 0) m0 = fmaxf(m0, mx);
                else if (ct == 1) m1 = fmaxf(m1, mx);
                else if (ct == 2) m2 = fmaxf(m2, mx);
                else m3 = fmaxf(m3, mx);
            }
        }
        // rare tiles (d > 16): serial path
        for (int t = 1; t < ntile; ++t) {
            int bkt = bucket[(long)node * CAP + t * 16 + c16];
            unsigned su = (unsigned)bkt < (unsigned)N ? (unsigned)bkt : 0u;
            const half8* vrt = (const half8*)(V + (long)su * 64);
            half8 a0 = vrt[r16] + u0A;
            half8 a1 = vrt[4 + r16] + u0B;
            #pragma unroll
            for (int j = 0; j < 8; ++j) {
                a0[j] = a0[j] > (f16)0 ? a0[j] : (f16)0;
                a1[j] = a1[j] > (f16)0 ? a1[j] : (f16)0;
            }
            const f32x4 z = {0.f, 0.f, 0.f, 0.f};
            #pragma unroll
            for (int ct = 0; ct < 4; ++ct) {
                f32x4 acc = __builtin_amdgcn_mfma_f32_16x16x32_f16(a0, WB[ct * 2 + 0][lane], z, 0, 0, 0);
                acc = __builtin_amdgcn_mfma_f32_16x16x32_f16(a1, WB[ct * 2 + 1][lane], acc, 0, 0, 0);
                float mx = -INFINITY;
                #pragma unroll
                for (int r = 0; r < 4; ++r) {
                    int row = t * 16 + r16 * 4 + r;
                    float val = (row < d) ? acc[r] : -INFINITY;
                    mx = fmaxf(mx, val);
                }
                mx = fmaxf(mx, __shfl_xor(mx, 16));
                mx = fmaxf(mx, __shfl_xor(mx, 32));
                if (ct == 0) m0 = fmaxf(m0, mx);
                else if (ct == 1) m1 = fmaxf(m1, mx);
                else if (ct == 2) m2 = fmaxf(m2, mx);
                else m3 = fmaxf(m3, mx);
            }
        }

        float sel = (r16 == 0) ? m0 : (r16 == 1) ? m1 : (r16 == 2) ? m2 : m3;
        float aggv = (d > 0) ? sel + bbv : 0.f;
        float bn = (aggv - mm) * rs * g + be;
        Fout[(long)node * 64 + lane] = fmaxf(bn, 0.f);

        // rotate pipeline registers
        v0A = v1A; v0B = v1B; v1A = v2A; v1B = v2B;
        u0A = u1A; u0B = u1B;
        bkt2 = bkt3;
    }
}

// ---------------- dense head: thread per node -------------------------------
__global__ __launch_bounds__(256) void head_kernel(
    const float* __restrict__ F,
    const float* __restrict__ lw1, const float* __restrict__ lb1,
    const float* __restrict__ lw2, const float* __restrict__ lb2,
    const float* __restrict__ lw3, const float* __restrict__ lb3,
    const float* __restrict__ lw4, const float* __restrict__ lb4,
    int N, float* __restrict__ out)
{
    __shared__ float W1[64][64];
    __shared__ float W2[64][32];
    __shared__ float W3[32][16];
    __shared__ float W4[16][3];
    __shared__ float B1[64], B2[32], B3[16], B4[3];
    int tid = threadIdx.x;
    for (int i = tid; i < 64 * 64; i += blockDim.x) W1[i >> 6][i & 63] = lw1[i];
    for (int i = tid; i < 64 * 32; i += blockDim.x) W2[i >> 5][i & 31] = lw2[i];
    for (int i = tid; i < 32 * 16; i += blockDim.x) W3[i >> 4][i & 15] = lw3[i];
    for (int i = tid; i < 16 * 3;  i += blockDim.x) W4[i / 3][i % 3]  = lw4[i];
    if (tid < 64) B1[tid] = lb1[tid];
    if (tid < 32) B2[tid] = lb2[tid];
    if (tid < 16) B3[tid] = lb3[tid];
    if (tid < 3)  B4[tid] = lb4[tid];
    __syncthreads();

    int n = blockIdx.x * blockDim.x + tid;
    if (n >= N) return;
    const float* f = F + (long)n * 64;

    float h1[64];
    #pragma unroll
    for (int o = 0; o < 64; ++o) h1[o] = B1[o];
    for (int k = 0; k < 64; ++k) {
        float c = f[k];
        #pragma unroll
        for (int o = 0; o < 64; ++o) h1[o] = fmaf(c, W1[k][o], h1[o]);
    }
    float h2[32];
    #pragma unroll
    for (int o = 0; o < 32; ++o) h2[o] = B2[o];
    #pragma unroll
    for (int k = 0; k < 64; ++k) {
        float c = fmaxf(h1[k], 0.f);
        #pragma unroll
        for (int o = 0; o < 32; ++o) h2[o] = fmaf(c, W2[k][o], h2[o]);
    }
    float h3[16];
    #pragma unroll
    for (int o = 0; o < 16; ++o) h3[o] = B3[o];
    #pragma unroll
    for (int k = 0; k < 32; ++k) {
        float c = fmaxf(h2[k], 0.f);
        #pragma unroll
        for (int o = 0; o < 16; ++o) h3[o] = fmaf(c, W3[k][o], h3[o]);
    }
    float o0 = B4[0], o1 = B4[1], o2 = B4[2];
    #pragma unroll
    for (int k = 0; k < 16; ++k) {
        float c = fmaxf(h3[k], 0.f);
        o0 = fmaf(c, W4[k][0], o0);
        o1 = fmaf(c, W4[k][1], o1);
        o2 = fmaf(c, W4[k][2], o2);
    }
    out[(long)n * 3 + 0] = o0;
    out[(long)n * 3 + 1] = o1;
    out[(long)n * 3 + 2] = o2;
}

// ---------------------------------------------------------------------------
extern "C" void kernel_launch(void* const* d_in, const int* in_sizes, int n_in,
                              void* d_out, int out_size, void* d_ws, size_t ws_size,
                              hipStream_t stream)
{
    const float* x   = (const float*)d_in[0];
    const int*   ei  = (const int*)d_in[1];
    int N = in_sizes[0] / 3;
    int E = in_sizes[1] / 2;

    const float* w1a = (const float*)d_in[2];  const float* b1a = (const float*)d_in[3];
    const float* w1b = (const float*)d_in[4];  const float* b1b = (const float*)d_in[5];
    const float* w2a = (const float*)d_in[6];  const float* b2a = (const float*)d_in[7];
    const float* w2b = (const float*)d_in[8];  const float* b2b = (const float*)d_in[9];
    const float* w3a = (const float*)d_in[10]; const float* b3a = (const float*)d_in[11];
    const float* w3b = (const float*)d_in[12]; const float* b3b = (const float*)d_in[13];
    const float* bn1g = (const float*)d_in[14]; const float* bn1b = (const float*)d_in[15];
    const float* bn1m = (const float*)d_in[16]; const float* bn1v = (const float*)d_in[17];
    const float* bn2g = (const float*)d_in[18]; const float* bn2b = (const float*)d_in[19];
    const float* bn2m = (const float*)d_in[20]; const float* bn2v = (const float*)d_in[21];
    const float* bn3g = (const float*)d_in[22]; const float* bn3b = (const float*)d_in[23];
    const float* bn3m = (const float*)d_in[24]; const float* bn3v = (const float*)d_in[25];
    const float* lw1 = (const float*)d_in[26]; const float* lb1 = (const float*)d_in[27];
    const float* lw2 = (const float*)d_in[28]; const float* lb2 = (const float*)d_in[29];
    const float* lw3 = (const float*)d_in[30]; const float* lb3 = (const float*)d_in[31];
    const float* lw4 = (const float*)d_in[32]; const float* lb4 = (const float*)d_in[33];
    float* out = (float*)d_out;

    // workspace layout (256B aligned slices)
    char* ws = (char*)d_ws;
    size_t off = 0;
    auto alloc = [&](size_t bytes) { void* p = ws + off; off += (bytes + 255) & ~(size_t)255; return p; };
    int*   deg    = (int*)  alloc((size_t)N * sizeof(int));
    int*   bucket = (int*)  alloc((size_t)N * CAP * sizeof(int));
    f16*   U      = (f16*)  alloc((size_t)N * 64 * sizeof(f16));
    f16*   V      = (f16*)  alloc((size_t)N * 64 * sizeof(f16));
    float* F      = (float*)alloc((size_t)N * 64 * sizeof(float));
    (void)ws_size; (void)n_in; (void)out_size;

    hipMemsetAsync(deg, 0, (size_t)N * sizeof(int), stream);
    build_buckets<<<(E + 255) / 256, 256, 0, stream>>>(ei, E, deg, bucket);

    int uv_grid   = (2 * N + 255) / 256;
    int node_blocks = 2048;            // 8192 waves, ~13-node chunks
    int nd_grid   = (N + 255) / 256;

    // layer 1
    uv_kernel<<<uv_grid, 256, 0, stream>>>(x, 3, 3, N, w1a, b1a, U, V);
    node_kernel<<<node_blocks, 256, 0, stream>>>(U, V, deg, bucket, w1b, b1b,
                                                 bn1g, bn1b, bn1m, bn1v, N, F);
    // layer 2
    uv_kernel<<<uv_grid, 256, 0, stream>>>(F, 64, 64, N, w2a, b2a, U, V);
    node_kernel<<<node_blocks, 256, 0, stream>>>(U, V, deg, bucket, w2b, b2b,
                                                 bn2g, bn2b, bn2m, bn2v, N, F);
    // layer 3
    uv_kernel<<<uv_grid, 256, 0, stream>>>(F, 64, 64, N, w3a, b3a, U, V);
    node_kernel<<<node_blocks, 256, 0, stream>>>(U, V, deg, bucket, w3b, b3b,
                                                 bn3g, bn3b, bn3m, bn3v, N, F);
    // head
    head_kernel<<<nd_grid, 256, 0, stream>>>(F, lw1, lb1, lw2, lb2, lw3, lb3,
                                             lw4, lb4, N, out);
}

// Round 14
// 550.051 us; speedup vs baseline: 1.8215x; 1.0148x over previous
//
#include <hip/hip_runtime.h>

#define CAP 64
#define BN_EPS 1e-5f

typedef _Float16 f16;
typedef _Float16 half8 __attribute__((ext_vector_type(8)));
typedef float f32x4 __attribute__((ext_vector_type(4)));

// ---------------- bucket build: CSR-lite with fixed capacity ----------------
__global__ __launch_bounds__(256) void build_buckets(
    const int* __restrict__ ei, int E,
    int* __restrict__ deg, int* __restrict__ bucket)
{
    int e = blockIdx.x * blockDim.x + threadIdx.x;
    if (e >= E) return;
    int src = ei[e];
    int dst = ei[E + e];
    int slot = atomicAdd(&deg[dst], 1);
    if (slot < CAP) bucket[dst * CAP + slot] = src;
}

// ---------------- uv2: 16 threads/node, float4 LDS weight reads -------------
// u = f@(A-B)+ba, v = f@B, both f16. thread sub: half=sub>>3 (0:U,1:V),
// og=(sub&7)*8 output channels.
template<typename T, int K>
__global__ __launch_bounds__(256) void uv2_kernel(
    const T* __restrict__ feat, int N,
    const float* __restrict__ wa, const float* __restrict__ ba,
    f16* __restrict__ U, f16* __restrict__ V)
{
    __shared__ float Wlds[2][K][64];
    __shared__ float blds[64];
    int tid = threadIdx.x;
    for (int idx = tid; idx < 2 * K * 64; idx += 256) {
        int half = idx / (K * 64);
        int rem = idx - half * (K * 64);
        int k = rem >> 6, o = rem & 63;
        float wB = wa[(K + k) * 64 + o];
        Wlds[half][k][o] = (half == 0) ? (wa[k * 64 + o] - wB) : wB;
    }
    if (tid < 64) blds[tid] = ba[tid];
    __syncthreads();

    long t = (long)blockIdx.x * 256 + tid;
    if (t >= (long)N * 16) return;
    int node = (int)(t >> 4);
    int sub = (int)(t & 15);
    int half = sub >> 3;          // 0: U, 1: V
    int og = (sub & 7) * 8;       // output group base

    float acc[8];
    #pragma unroll
    for (int j = 0; j < 8; ++j) acc[j] = (half == 0) ? blds[og + j] : 0.f;

    if constexpr (K == 3) {
        const T* f = feat + (long)node * K;
        #pragma unroll
        for (int k = 0; k < 3; ++k) {
            float c = (float)f[k];
            float4 w0 = *(const float4*)&Wlds[half][k][og];
            float4 w1 = *(const float4*)&Wlds[half][k][og + 4];
            acc[0] = fmaf(c, w0.x, acc[0]); acc[1] = fmaf(c, w0.y, acc[1]);
            acc[2] = fmaf(c, w0.z, acc[2]); acc[3] = fmaf(c, w0.w, acc[3]);
            acc[4] = fmaf(c, w1.x, acc[4]); acc[5] = fmaf(c, w1.y, acc[5]);
            acc[6] = fmaf(c, w1.z, acc[6]); acc[7] = fmaf(c, w1.w, acc[7]);
        }
    } else {
        const half8* fp = (const half8*)(feat + (long)node * K);
        half8 fr[K / 8];
        #pragma unroll
        for (int q = 0; q < K / 8; ++q) fr[q] = fp[q];
        #pragma unroll
        for (int k = 0; k < K; ++k) {
            float c = (float)fr[k >> 3][k & 7];   // fully unrolled: static idx
            float4 w0 = *(const float4*)&Wlds[half][k][og];
            float4 w1 = *(const float4*)&Wlds[half][k][og + 4];
            acc[0] = fmaf(c, w0.x, acc[0]); acc[1] = fmaf(c, w0.y, acc[1]);
            acc[2] = fmaf(c, w0.z, acc[2]); acc[3] = fmaf(c, w0.w, acc[3]);
            acc[4] = fmaf(c, w1.x, acc[4]); acc[5] = fmaf(c, w1.y, acc[5]);
            acc[6] = fmaf(c, w1.z, acc[6]); acc[7] = fmaf(c, w1.w, acc[7]);
        }
    }

    half8 h;
    #pragma unroll
    for (int j = 0; j < 8; ++j) h[j] = (f16)acc[j];
    f16* dstp = (half == 0 ? U : V) + (long)node * 64 + og;
    *(half8*)dstp = h;
}

// ---------------- node kernel: wave per node, MFMA, depth-3 V pipeline ------
// A frag: lane holds A[row=lane&15][k=32*s+8*(lane>>4)+j]
// B frag in LDS. D frag: lane holds D[row=4*(lane>>4)+r][col=16*ct+(lane&15)]
// launch_bounds(256,4): VGPR cap 128 (round-9's (256,8) spilled: 524 MB writes).
__global__ __launch_bounds__(256, 4) void node_kernel(
    const f16* __restrict__ U, const f16* __restrict__ V,
    const int* __restrict__ deg, const int* __restrict__ bucket,
    const float* __restrict__ wb, const float* __restrict__ bb,
    const float* __restrict__ bng, const float* __restrict__ bnb,
    const float* __restrict__ bnm, const float* __restrict__ bnv,
    int N, f16* __restrict__ Fout)
{
    const int lane = threadIdx.x & 63;
    const int r16 = lane >> 4, c16 = lane & 15;
    const int wid = (blockIdx.x * blockDim.x + threadIdx.x) >> 6;
    const int nwaves = (gridDim.x * blockDim.x) >> 6;

    // Wb fragments in LDS: WB[f=ct*2+s][lane] = half8 (8 KB).
    __shared__ half8 WB[8][64];
    for (int idx = threadIdx.x; idx < 8 * 64; idx += blockDim.x) {
        int f = idx >> 6, l = idx & 63;
        int lr = l >> 4, lc = l & 15;
        int s = f & 1, ct = f >> 1;
        half8 h;
        #pragma unroll
        for (int j = 0; j < 8; ++j) {
            int k = 32 * s + 8 * lr + j;
            h[j] = (f16)wb[k * 64 + 16 * ct + lc];
        }
        WB[f][l] = h;
    }
    __syncthreads();

    const float bbv = bb[lane];
    const float g = bng[lane], be = bnb[lane];
    const float rs = rsqrtf(bnv[lane] + BN_EPS), mm = bnm[lane];

    int chunk = (N + nwaves - 1) / nwaves;
    int n0 = wid * chunk;
    int n1 = n0 + chunk; if (n1 > N) n1 = N;
    if (n0 >= n1) return;

    // block-load this chunk's degrees (chunk <= 64), access via shfl
    int dval = 0;
    if (lane < n1 - n0) dval = deg[n0 + lane];
    dval = dval > CAP ? CAP : dval;

    auto nclamp = [&](int n) { return n < n1 ? n : n1 - 1; };

    // prologue: bucket rows for n0..n0+2; V gathers for n0, n0+1; U for n0
    int bkt0 = bucket[(long)n0 * CAP + c16];
    int bkt1 = bucket[(long)nclamp(n0 + 1) * CAP + c16];
    int bkt2 = bucket[(long)nclamp(n0 + 2) * CAP + c16];

    unsigned s0 = (unsigned)bkt0 < (unsigned)N ? (unsigned)bkt0 : 0u;
    unsigned s1 = (unsigned)bkt1 < (unsigned)N ? (unsigned)bkt1 : 0u;
    const half8* vp0 = (const half8*)(V + (long)s0 * 64);
    const half8* vp1 = (const half8*)(V + (long)s1 * 64);
    half8 v0A = vp0[r16], v0B = vp0[4 + r16];
    half8 v1A = vp1[r16], v1B = vp1[4 + r16];
    const half8* up0 = (const half8*)(U + (long)n0 * 64);
    half8 u0A = up0[r16], u0B = up0[4 + r16];

    for (int node = n0; node < n1; ++node) {
        // issue: V gather for node+2 (bkt2 loaded 2 iters ago)
        unsigned s2 = (unsigned)bkt2 < (unsigned)N ? (unsigned)bkt2 : 0u;
        const half8* vp2 = (const half8*)(V + (long)s2 * 64);
        half8 v2A = vp2[r16], v2B = vp2[4 + r16];
        // issue: bucket row for node+3
        int bkt3 = bucket[(long)nclamp(node + 3) * CAP + c16];
        // issue: U row for node+1
        const half8* up1 = (const half8*)(U + (long)nclamp(node + 1) * 64);
        half8 u1A = up1[r16], u1B = up1[4 + r16];

        int d = __shfl(dval, node - n0);

        float m0 = -INFINITY, m1 = -INFINITY, m2 = -INFINITY, m3 = -INFINITY;
        int ntile = (d + 15) >> 4;

        if (ntile > 0) {
            // tile 0: data already gathered (v0A/v0B)
            half8 a0 = v0A + u0A;
            half8 a1 = v0B + u0B;
            #pragma unroll
            for (int j = 0; j < 8; ++j) {
                a0[j] = a0[j] > (f16)0 ? a0[j] : (f16)0;
                a1[j] = a1[j] > (f16)0 ? a1[j] : (f16)0;
            }
            const f32x4 z = {0.f, 0.f, 0.f, 0.f};
            #pragma unroll
            for (int ct = 0; ct < 4; ++ct) {
                f32x4 acc = __builtin_amdgcn_mfma_f32_16x16x32_f16(a0, WB[ct * 2 + 0][lane], z, 0, 0, 0);
                acc = __builtin_amdgcn_mfma_f32_16x16x32_f16(a1, WB[ct * 2 + 1][lane], acc, 0, 0, 0);
                float mx = -INFINITY;
                #pragma unroll
                for (int r = 0; r < 4; ++r) {
                    int row = r16 * 4 + r;
                    float val = (row < d) ? acc[r] : -INFINITY;
                    mx = fmaxf(mx, val);
                }
                mx = fmaxf(mx, __shfl_xor(mx, 16));
                mx = fmaxf(mx, __shfl_xor(mx, 32));
                if (ct == 0) m0 = fmaxf(m0, mx);
                else if (ct == 1) m1 = fmaxf(m1, mx);
                else if (ct == 2) m2 = fmaxf(m2, mx);
                else m3 = fmaxf(m3, mx);
            }
        }
        // rare tiles (d > 16): serial path
        for (int t = 1; t < ntile; ++t) {
            int bkt = bucket[(long)node * CAP + t * 16 + c16];
            unsigned su = (unsigned)bkt < (unsigned)N ? (unsigned)bkt : 0u;
            const half8* vrt = (const half8*)(V + (long)su * 64);
            half8 a0 = vrt[r16] + u0A;
            half8 a1 = vrt[4 + r16] + u0B;
            #pragma unroll
            for (int j = 0; j < 8; ++j) {
                a0[j] = a0[j] > (f16)0 ? a0[j] : (f16)0;
                a1[j] = a1[j] > (f16)0 ? a1[j] : (f16)0;
            }
            const f32x4 z = {0.f, 0.f, 0.f, 0.f};
            #pragma unroll
            for (int ct = 0; ct < 4; ++ct) {
                f32x4 acc = __builtin_amdgcn_mfma_f32_16x16x32_f16(a0, WB[ct * 2 + 0][lane], z, 0, 0, 0);
                acc = __builtin_amdgcn_mfma_f32_16x16x32_f16(a1, WB[ct * 2 + 1][lane], acc, 0, 0, 0);
                float mx = -INFINITY;
                #pragma unroll
                for (int r = 0; r < 4; ++r) {
                    int row = t * 16 + r16 * 4 + r;
                    float val = (row < d) ? acc[r] : -INFINITY;
                    mx = fmaxf(mx, val);
                }
                mx = fmaxf(mx, __shfl_xor(mx, 16));
                mx = fmaxf(mx, __shfl_xor(mx, 32));
                if (ct == 0) m0 = fmaxf(m0, mx);
                else if (ct == 1) m1 = fmaxf(m1, mx);
                else if (ct == 2) m2 = fmaxf(m2, mx);
                else m3 = fmaxf(m3, mx);
            }
        }

        float sel = (r16 == 0) ? m0 : (r16 == 1) ? m1 : (r16 == 2) ? m2 : m3;
        float aggv = (d > 0) ? sel + bbv : 0.f;
        float bn = (aggv - mm) * rs * g + be;
        Fout[(long)node * 64 + lane] = (f16)fmaxf(bn, 0.f);

        // rotate pipeline registers
        v0A = v1A; v0B = v1B; v1A = v2A; v1B = v2B;
        u0A = u1A; u0B = u1B;
        bkt2 = bkt3;
    }
}

// ---------------- dense head: thread per node (F in f16) --------------------
__global__ __launch_bounds__(256) void head_kernel(
    const f16* __restrict__ F,
    const float* __restrict__ lw1, const float* __restrict__ lb1,
    const float* __restrict__ lw2, const float* __restrict__ lb2,
    const float* __restrict__ lw3, const float* __restrict__ lb3,
    const float* __restrict__ lw4, const float* __restrict__ lb4,
    int N, float* __restrict__ out)
{
    __shared__ float W1[64][64];
    __shared__ float W2[64][32];
    __shared__ float W3[32][16];
    __shared__ float W4[16][3];
    __shared__ float B1[64], B2[32], B3[16], B4[3];
    int tid = threadIdx.x;
    for (int i = tid; i < 64 * 64; i += blockDim.x) W1[i >> 6][i & 63] = lw1[i];
    for (int i = tid; i < 64 * 32; i += blockDim.x) W2[i >> 5][i & 31] = lw2[i];
    for (int i = tid; i < 32 * 16; i += blockDim.x) W3[i >> 4][i & 15] = lw3[i];
    for (int i = tid; i < 16 * 3;  i += blockDim.x) W4[i / 3][i % 3]  = lw4[i];
    if (tid < 64) B1[tid] = lb1[tid];
    if (tid < 32) B2[tid] = lb2[tid];
    if (tid < 16) B3[tid] = lb3[tid];
    if (tid < 3)  B4[tid] = lb4[tid];
    __syncthreads();

    int n = blockIdx.x * blockDim.x + tid;
    if (n >= N) return;
    const f16* f = F + (long)n * 64;

    float h1[64];
    #pragma unroll
    for (int o = 0; o < 64; ++o) h1[o] = B1[o];
    for (int k = 0; k < 64; ++k) {
        float c = (float)f[k];
        #pragma unroll
        for (int o = 0; o < 64; ++o) h1[o] = fmaf(c, W1[k][o], h1[o]);
    }
    float h2[32];
    #pragma unroll
    for (int o = 0; o < 32; ++o) h2[o] = B2[o];
    #pragma unroll
    for (int k = 0; k < 64; ++k) {
        float c = fmaxf(h1[k], 0.f);
        #pragma unroll
        for (int o = 0; o < 32; ++o) h2[o] = fmaf(c, W2[k][o], h2[o]);
    }
    float h3[16];
    #pragma unroll
    for (int o = 0; o < 16; ++o) h3[o] = B3[o];
    #pragma unroll
    for (int k = 0; k < 32; ++k) {
        float c = fmaxf(h2[k], 0.f);
        #pragma unroll
        for (int o = 0; o < 16; ++o) h3[o] = fmaf(c, W3[k][o], h3[o]);
    }
    float o0 = B4[0], o1 = B4[1], o2 = B4[2];
    #pragma unroll
    for (int k = 0; k < 16; ++k) {
        float c = fmaxf(h3[k], 0.f);
        o0 = fmaf(c, W4[k][0], o0);
        o1 = fmaf(c, W4[k][1], o1);
        o2 = fmaf(c, W4[k][2], o2);
    }
    out[(long)n * 3 + 0] = o0;
    out[(long)n * 3 + 1] = o1;
    out[(long)n * 3 + 2] = o2;
}

// ---------------------------------------------------------------------------
extern "C" void kernel_launch(void* const* d_in, const int* in_sizes, int n_in,
                              void* d_out, int out_size, void* d_ws, size_t ws_size,
                              hipStream_t stream)
{
    const float* x   = (const float*)d_in[0];
    const int*   ei  = (const int*)d_in[1];
    int N = in_sizes[0] / 3;
    int E = in_sizes[1] / 2;

    const float* w1a = (const float*)d_in[2];  const float* b1a = (const float*)d_in[3];
    const float* w1b = (const float*)d_in[4];  const float* b1b = (const float*)d_in[5];
    const float* w2a = (const float*)d_in[6];  const float* b2a = (const float*)d_in[7];
    const float* w2b = (const float*)d_in[8];  const float* b2b = (const float*)d_in[9];
    const float* w3a = (const float*)d_in[10]; const float* b3a = (const float*)d_in[11];
    const float* w3b = (const float*)d_in[12]; const float* b3b = (const float*)d_in[13];
    const float* bn1g = (const float*)d_in[14]; const float* bn1b = (const float*)d_in[15];
    const float* bn1m = (const float*)d_in[16]; const float* bn1v = (const float*)d_in[17];
    const float* bn2g = (const float*)d_in[18]; const float* bn2b = (const float*)d_in[19];
    const float* bn2m = (const float*)d_in[20]; const float* bn2v = (const float*)d_in[21];
    const float* bn3g = (const float*)d_in[22]; const float* bn3b = (const float*)d_in[23];
    const float* bn3m = (const float*)d_in[24]; const float* bn3v = (const float*)d_in[25];
    const float* lw1 = (const float*)d_in[26]; const float* lb1 = (const float*)d_in[27];
    const float* lw2 = (const float*)d_in[28]; const float* lb2 = (const float*)d_in[29];
    const float* lw3 = (const float*)d_in[30]; const float* lb3 = (const float*)d_in[31];
    const float* lw4 = (const float*)d_in[32]; const float* lb4 = (const float*)d_in[33];
    float* out = (float*)d_out;

    // workspace layout (256B aligned slices)
    char* ws = (char*)d_ws;
    size_t off = 0;
    auto alloc = [&](size_t bytes) { void* p = ws + off; off += (bytes + 255) & ~(size_t)255; return p; };
    int*   deg    = (int*)  alloc((size_t)N * sizeof(int));
    int*   bucket = (int*)  alloc((size_t)N * CAP * sizeof(int));
    f16*   U      = (f16*)  alloc((size_t)N * 64 * sizeof(f16));
    f16*   V      = (f16*)  alloc((size_t)N * 64 * sizeof(f16));
    f16*   F      = (f16*)  alloc((size_t)N * 64 * sizeof(f16));
    (void)ws_size; (void)n_in; (void)out_size;

    hipMemsetAsync(deg, 0, (size_t)N * sizeof(int), stream);
    build_buckets<<<(E + 255) / 256, 256, 0, stream>>>(ei, E, deg, bucket);

    long uv_threads = (long)N * 16;
    int uv_grid   = (int)((uv_threads + 255) / 256);
    int node_blocks = 2048;            // 8192 waves, ~13-node chunks
    int nd_grid   = (N + 255) / 256;

    // layer 1
    uv2_kernel<float, 3><<<uv_grid, 256, 0, stream>>>(x, N, w1a, b1a, U, V);
    node_kernel<<<node_blocks, 256, 0, stream>>>(U, V, deg, bucket, w1b, b1b,
                                                 bn1g, bn1b, bn1m, bn1v, N, F);
    // layer 2
    uv2_kernel<f16, 64><<<uv_grid, 256, 0, stream>>>(F, N, w2a, b2a, U, V);
    node_kernel<<<node_blocks, 256, 0, stream>>>(U, V, deg, bucket, w2b, b2b,
                                                 bn2g, bn2b, bn2m, bn2v, N, F);
    // layer 3
    uv2_kernel<f16, 64><<<uv_grid, 256, 0, stream>>>(F, N, w3a, b3a, U, V);
    node_kernel<<<node_blocks, 256, 0, stream>>>(U, V, deg, bucket, w3b, b3b,
                                                 bn3g, bn3b, bn3m, bn3v, N, F);
    // head
    head_kernel<<<nd_grid, 256, 0, stream>>>(F, lw1, lb1, lw2, lb2, lw3, lb3,
                                             lw4, lb4, N, out);
}